// Round 5
// baseline (383.696 us; speedup 1.0000x reference)
//
#include <hip/hip_runtime.h>

// SSIM loss, fused single-pass — NO-LDS version.
// R3 post-mortem: LDS tiling (76 KiB) capped occupancy at 2 blocks/CU (20.5%);
// stage->barrier->compute serialized per block; VALUBusy 32%, HBM 12% => latency-bound.
// Fix: drop LDS. Each thread owns 2 output columns and walks a 16-row band,
// reading the 8-float horizontal window union as 5 aligned float2 global loads
// per image per row (neighbor lanes share cache lines -> L1 serves overlap).
// Vertical 7-window via the proven 8-slot register ring (fully unrolled =>
// static indices, no scratch). No barriers, no bank conflicts, occupancy
// VGPR-bound (~4 waves/SIMD).
//
// Edges: x handled branchlessly (clamped addresses + cndmask-to-zero on the 4
// possibly-OOB chunks); y handled by a wave-uniform branch (zeros outside).

constexpr int IMG = 512;
constexpr int BAND = 16;               // output rows per block
constexpr float C1 = 1.0e-4f;          // 0.01^2
constexpr float C2 = 9.0e-4f;          // 0.03^2
constexpr double INV_N = 1.0 / (64.0 * 512.0 * 512.0);

__global__ __launch_bounds__(256, 4)
void ssim_fused(const float* __restrict__ img1, const float* __restrict__ img2,
                double* __restrict__ partial) {
    __shared__ float wpart[4];

    const int tid = threadIdx.x;
    const int y0 = blockIdx.x * BAND;
    const size_t ib = (size_t)blockIdx.y * (IMG * IMG);
    const float* b1 = img1 + ib;
    const float* b2 = img2 + ib;

    // thread owns cols (2c, 2c+1); window union = floats [2c-4 .. 2c+5]
    const int xb = 2 * tid;
    const int xo0 = max(xb - 4, 0);          // clamped chunk offsets (stay in-row)
    const int xo1 = max(xb - 2, 0);
    const int xo2 = xb;
    const int xo3 = min(xb + 2, IMG - 2);
    const int xo4 = min(xb + 4, IMG - 2);
    const bool p0 = (xb - 4) >= 0;           // chunk-valid predicates
    const bool p1 = (xb - 2) >= 0;
    const bool p3 = (xb + 2) < IMG;
    const bool p4 = (xb + 4) < IMG;

    // 8-slot rings: 5 quantities x 2 columns (live set ~70 regs after unroll)
    float rA0[8], rA1[8], rB0[8], rB1[8], rAA0[8], rAA1[8],
          rBB0[8], rBB1[8], rAB0[8], rAB1[8];
    float SA0 = 0, SA1 = 0, SB0 = 0, SB1 = 0, SAA0 = 0, SAA1 = 0,
          SBB0 = 0, SBB1 = 0, SAB0 = 0, SAB1 = 0;
    float acc = 0.f;

    // horizontal 7-tap sums of image row `row` -> ring slot k (static after unroll)
    auto hrow = [&](int row, int k) {
        float2 zz = make_float2(0.f, 0.f);
        float2 a0 = zz, a1 = zz, a2 = zz, a3 = zz, a4 = zz;
        float2 c0 = zz, c1v = zz, c2v = zz, c3 = zz, c4 = zz;
        if ((unsigned)row < (unsigned)IMG) {             // wave-uniform branch
            const float* r1 = b1 + row * IMG;
            const float* r2 = b2 + row * IMG;
            a0 = *(const float2*)(r1 + xo0);
            a1 = *(const float2*)(r1 + xo1);
            a2 = *(const float2*)(r1 + xo2);
            a3 = *(const float2*)(r1 + xo3);
            a4 = *(const float2*)(r1 + xo4);
            c0 = *(const float2*)(r2 + xo0);
            c1v = *(const float2*)(r2 + xo1);
            c2v = *(const float2*)(r2 + xo2);
            c3 = *(const float2*)(r2 + xo3);
            c4 = *(const float2*)(r2 + xo4);
            a0 = p0 ? a0 : zz;  c0 = p0 ? c0 : zz;       // zero-pad x edges
            a1 = p1 ? a1 : zz;  c1v = p1 ? c1v : zz;
            a3 = p3 ? a3 : zz;  c3 = p3 ? c3 : zz;
            a4 = p4 ? a4 : zz;  c4 = p4 ? c4 : zz;
        }
        float va1 = a0.y, va2 = a1.x, va3 = a1.y, va4 = a2.x,
              va5 = a2.y, va6 = a3.x, va7 = a3.y, va8 = a4.x;
        float vb1 = c0.y, vb2 = c1v.x, vb3 = c1v.y, vb4 = c2v.x,
              vb5 = c2v.y, vb6 = c3.x, vb7 = c3.y, vb8 = c4.x;

        float sA = ((va1 + va2) + (va3 + va4)) + ((va5 + va6) + va7);
        rA0[k] = sA;
        rA1[k] = (sA - va1) + va8;

        float sB = ((vb1 + vb2) + (vb3 + vb4)) + ((vb5 + vb6) + vb7);
        rB0[k] = sB;
        rB1[k] = (sB - vb1) + vb8;

        float sAA = fmaf(va7, va7, fmaf(va6, va6, fmaf(va5, va5,
                    fmaf(va4, va4, fmaf(va3, va3, fmaf(va2, va2, va1 * va1))))));
        rAA0[k] = sAA;
        rAA1[k] = fmaf(va8, va8, sAA - va1 * va1);

        float sBB = fmaf(vb7, vb7, fmaf(vb6, vb6, fmaf(vb5, vb5,
                    fmaf(vb4, vb4, fmaf(vb3, vb3, fmaf(vb2, vb2, vb1 * vb1))))));
        rBB0[k] = sBB;
        rBB1[k] = fmaf(vb8, vb8, sBB - vb1 * vb1);

        float sAB = fmaf(va7, vb7, fmaf(va6, vb6, fmaf(va5, vb5,
                    fmaf(va4, vb4, fmaf(va3, vb3, fmaf(va2, vb2, va1 * vb1))))));
        rAB0[k] = sAB;
        rAB1[k] = fmaf(va8, vb8, sAB - va1 * vb1);
    };

    // prime ring: image rows y0-3 .. y0+2 -> slots 0..5
#pragma unroll
    for (int k = 0; k < 6; ++k) {
        hrow(y0 - 3 + k, k);
        SA0 += rA0[k]; SA1 += rA1[k]; SB0 += rB0[k]; SB1 += rB1[k];
        SAA0 += rAA0[k]; SAA1 += rAA1[k]; SBB0 += rBB0[k]; SBB1 += rBB1[k];
        SAB0 += rAB0[k]; SAB1 += rAB1[k];
    }

    // 16 output rows, fully unrolled (static ring indices)
#pragma unroll
    for (int t = 0; t < BAND; ++t) {
        const int kn = (t + 6) & 7;   // incoming image row y0+t+3
        const int ko = t & 7;         // outgoing image row y0+t-3
        hrow(y0 + t + 3, kn);
        SA0 += rA0[kn]; SA1 += rA1[kn]; SB0 += rB0[kn]; SB1 += rB1[kn];
        SAA0 += rAA0[kn]; SAA1 += rAA1[kn]; SBB0 += rBB0[kn]; SBB1 += rBB1[kn];
        SAB0 += rAB0[kn]; SAB1 += rAB1[kn];

        {   // SSIM, col 2c
            float m12 = SA0 * SB0, m11 = SA0 * SA0, m22 = SB0 * SB0;
            float num = fmaf(2.f, m12, C1) * fmaf(2.f, SAB0 - m12, C2);
            float den = (m11 + m22 + C1) * ((SAA0 - m11) + (SBB0 - m22) + C2);
            acc = fmaf(num, __builtin_amdgcn_rcpf(den), acc);
        }
        {   // SSIM, col 2c+1
            float m12 = SA1 * SB1, m11 = SA1 * SA1, m22 = SB1 * SB1;
            float num = fmaf(2.f, m12, C1) * fmaf(2.f, SAB1 - m12, C2);
            float den = (m11 + m22 + C1) * ((SAA1 - m11) + (SBB1 - m22) + C2);
            acc = fmaf(num, __builtin_amdgcn_rcpf(den), acc);
        }

        SA0 -= rA0[ko]; SA1 -= rA1[ko]; SB0 -= rB0[ko]; SB1 -= rB1[ko];
        SAA0 -= rAA0[ko]; SAA1 -= rAA1[ko]; SBB0 -= rBB0[ko]; SBB1 -= rBB1[ko];
        SAB0 -= rAB0[ko]; SAB1 -= rAB1[ko];
    }

    // ---- reduce: wave shuffle -> LDS -> one double atomic per block ----
#pragma unroll
    for (int off = 32; off > 0; off >>= 1)
        acc += __shfl_xor(acc, off);
    if ((tid & 63) == 0) wpart[tid >> 6] = acc;
    __syncthreads();
    if (tid == 0)
        atomicAdd(partial, (double)((wpart[0] + wpart[1]) + (wpart[2] + wpart[3])));
}

__global__ void ssim_finalize(const double* __restrict__ partial,
                              float* __restrict__ out) {
    out[0] = (float)(1.0 - partial[0] * INV_N);
}

extern "C" void kernel_launch(void* const* d_in, const int* in_sizes, int n_in,
                              void* d_out, int out_size, void* d_ws, size_t ws_size,
                              hipStream_t stream) {
    const float* img1 = (const float*)d_in[0];
    const float* img2 = (const float*)d_in[1];
    float* out = (float*)d_out;
    double* partial = (double*)d_ws;

    hipMemsetAsync(partial, 0, sizeof(double), stream);

    dim3 grid(IMG / BAND, 64);    // 32 bands x 64 images = 2048 blocks
    ssim_fused<<<grid, 256, 0, stream>>>(img1, img2, partial);
    ssim_finalize<<<1, 1, 0, stream>>>(partial, out);
}

// Round 7
// 268.810 us; speedup vs baseline: 1.4274x; 1.4274x over previous
//
#include <hip/hip_runtime.h>

// SSIM loss, fused single-pass — NO-LDS version, spill-fixed.
// R5 post-mortem: __launch_bounds__(256,4) capped unified VGPR+AGPR at 128/wave;
// ring live-set (~150) spilled to scratch -> WRITE_SIZE 516 MB, 285 us.
// Fix: (256,2) -> 256-reg budget (R3 proved the ring fits: 88 VGPR + AGPRs).
// Occupancy becomes register-bound (~3 waves/SIMD); no barriers, so independent
// waves still overlap loads with compute.

constexpr int IMG = 512;
constexpr int BAND = 16;               // output rows per block
constexpr float C1 = 1.0e-4f;          // 0.01^2
constexpr float C2 = 9.0e-4f;          // 0.03^2
constexpr double INV_N = 1.0 / (64.0 * 512.0 * 512.0);

__global__ __launch_bounds__(256, 2)
void ssim_fused(const float* __restrict__ img1, const float* __restrict__ img2,
                double* __restrict__ partial) {
    __shared__ float wpart[4];

    const int tid = threadIdx.x;
    const int y0 = blockIdx.x * BAND;
    const size_t ib = (size_t)blockIdx.y * (IMG * IMG);
    const float* b1 = img1 + ib;
    const float* b2 = img2 + ib;

    // thread owns cols (2c, 2c+1); window union = floats [2c-4 .. 2c+5]
    const int xb = 2 * tid;
    const int xo0 = max(xb - 4, 0);          // clamped chunk offsets (stay in-row)
    const int xo1 = max(xb - 2, 0);
    const int xo2 = xb;
    const int xo3 = min(xb + 2, IMG - 2);
    const int xo4 = min(xb + 4, IMG - 2);
    const bool p0 = (xb - 4) >= 0;           // chunk-valid predicates
    const bool p1 = (xb - 2) >= 0;
    const bool p3 = (xb + 2) < IMG;
    const bool p4 = (xb + 4) < IMG;

    // 8-slot rings: 5 quantities x 2 columns
    float rA0[8], rA1[8], rB0[8], rB1[8], rAA0[8], rAA1[8],
          rBB0[8], rBB1[8], rAB0[8], rAB1[8];
    float SA0 = 0, SA1 = 0, SB0 = 0, SB1 = 0, SAA0 = 0, SAA1 = 0,
          SBB0 = 0, SBB1 = 0, SAB0 = 0, SAB1 = 0;
    float acc = 0.f;

    // horizontal 7-tap sums of image row `row` -> ring slot k (static after unroll)
    auto hrow = [&](int row, int k) {
        float2 zz = make_float2(0.f, 0.f);
        float2 a0 = zz, a1 = zz, a2 = zz, a3 = zz, a4 = zz;
        float2 c0 = zz, c1v = zz, c2v = zz, c3 = zz, c4 = zz;
        if ((unsigned)row < (unsigned)IMG) {             // wave-uniform branch
            const float* r1 = b1 + row * IMG;
            const float* r2 = b2 + row * IMG;
            a0 = *(const float2*)(r1 + xo0);
            a1 = *(const float2*)(r1 + xo1);
            a2 = *(const float2*)(r1 + xo2);
            a3 = *(const float2*)(r1 + xo3);
            a4 = *(const float2*)(r1 + xo4);
            c0 = *(const float2*)(r2 + xo0);
            c1v = *(const float2*)(r2 + xo1);
            c2v = *(const float2*)(r2 + xo2);
            c3 = *(const float2*)(r2 + xo3);
            c4 = *(const float2*)(r2 + xo4);
            a0 = p0 ? a0 : zz;  c0 = p0 ? c0 : zz;       // zero-pad x edges
            a1 = p1 ? a1 : zz;  c1v = p1 ? c1v : zz;
            a3 = p3 ? a3 : zz;  c3 = p3 ? c3 : zz;
            a4 = p4 ? a4 : zz;  c4 = p4 ? c4 : zz;
        }
        float va1 = a0.y, va2 = a1.x, va3 = a1.y, va4 = a2.x,
              va5 = a2.y, va6 = a3.x, va7 = a3.y, va8 = a4.x;
        float vb1 = c0.y, vb2 = c1v.x, vb3 = c1v.y, vb4 = c2v.x,
              vb5 = c2v.y, vb6 = c3.x, vb7 = c3.y, vb8 = c4.x;

        float sA = ((va1 + va2) + (va3 + va4)) + ((va5 + va6) + va7);
        rA0[k] = sA;
        rA1[k] = (sA - va1) + va8;

        float sB = ((vb1 + vb2) + (vb3 + vb4)) + ((vb5 + vb6) + vb7);
        rB0[k] = sB;
        rB1[k] = (sB - vb1) + vb8;

        float sAA = fmaf(va7, va7, fmaf(va6, va6, fmaf(va5, va5,
                    fmaf(va4, va4, fmaf(va3, va3, fmaf(va2, va2, va1 * va1))))));
        rAA0[k] = sAA;
        rAA1[k] = fmaf(va8, va8, sAA - va1 * va1);

        float sBB = fmaf(vb7, vb7, fmaf(vb6, vb6, fmaf(vb5, vb5,
                    fmaf(vb4, vb4, fmaf(vb3, vb3, fmaf(vb2, vb2, vb1 * vb1))))));
        rBB0[k] = sBB;
        rBB1[k] = fmaf(vb8, vb8, sBB - vb1 * vb1);

        float sAB = fmaf(va7, vb7, fmaf(va6, vb6, fmaf(va5, vb5,
                    fmaf(va4, vb4, fmaf(va3, vb3, fmaf(va2, vb2, va1 * vb1))))));
        rAB0[k] = sAB;
        rAB1[k] = fmaf(va8, vb8, sAB - va1 * vb1);
    };

    // prime ring: image rows y0-3 .. y0+2 -> slots 0..5
#pragma unroll
    for (int k = 0; k < 6; ++k) {
        hrow(y0 - 3 + k, k);
        SA0 += rA0[k]; SA1 += rA1[k]; SB0 += rB0[k]; SB1 += rB1[k];
        SAA0 += rAA0[k]; SAA1 += rAA1[k]; SBB0 += rBB0[k]; SBB1 += rBB1[k];
        SAB0 += rAB0[k]; SAB1 += rAB1[k];
    }

    // 16 output rows, fully unrolled (static ring indices)
#pragma unroll
    for (int t = 0; t < BAND; ++t) {
        const int kn = (t + 6) & 7;   // incoming image row y0+t+3
        const int ko = t & 7;         // outgoing image row y0+t-3
        hrow(y0 + t + 3, kn);
        SA0 += rA0[kn]; SA1 += rA1[kn]; SB0 += rB0[kn]; SB1 += rB1[kn];
        SAA0 += rAA0[kn]; SAA1 += rAA1[kn]; SBB0 += rBB0[kn]; SBB1 += rBB1[kn];
        SAB0 += rAB0[kn]; SAB1 += rAB1[kn];

        {   // SSIM, col 2c
            float m12 = SA0 * SB0, m11 = SA0 * SA0, m22 = SB0 * SB0;
            float num = fmaf(2.f, m12, C1) * fmaf(2.f, SAB0 - m12, C2);
            float den = (m11 + m22 + C1) * ((SAA0 - m11) + (SBB0 - m22) + C2);
            acc = fmaf(num, __builtin_amdgcn_rcpf(den), acc);
        }
        {   // SSIM, col 2c+1
            float m12 = SA1 * SB1, m11 = SA1 * SA1, m22 = SB1 * SB1;
            float num = fmaf(2.f, m12, C1) * fmaf(2.f, SAB1 - m12, C2);
            float den = (m11 + m22 + C1) * ((SAA1 - m11) + (SBB1 - m22) + C2);
            acc = fmaf(num, __builtin_amdgcn_rcpf(den), acc);
        }

        SA0 -= rA0[ko]; SA1 -= rA1[ko]; SB0 -= rB0[ko]; SB1 -= rB1[ko];
        SAA0 -= rAA0[ko]; SAA1 -= rAA1[ko]; SBB0 -= rBB0[ko]; SBB1 -= rBB1[ko];
        SAB0 -= rAB0[ko]; SAB1 -= rAB1[ko];
    }

    // ---- reduce: wave shuffle -> LDS -> one double atomic per block ----
#pragma unroll
    for (int off = 32; off > 0; off >>= 1)
        acc += __shfl_xor(acc, off);
    if ((tid & 63) == 0) wpart[tid >> 6] = acc;
    __syncthreads();
    if (tid == 0)
        atomicAdd(partial, (double)((wpart[0] + wpart[1]) + (wpart[2] + wpart[3])));
}

__global__ void ssim_finalize(const double* __restrict__ partial,
                              float* __restrict__ out) {
    out[0] = (float)(1.0 - partial[0] * INV_N);
}

extern "C" void kernel_launch(void* const* d_in, const int* in_sizes, int n_in,
                              void* d_out, int out_size, void* d_ws, size_t ws_size,
                              hipStream_t stream) {
    const float* img1 = (const float*)d_in[0];
    const float* img2 = (const float*)d_in[1];
    float* out = (float*)d_out;
    double* partial = (double*)d_ws;

    hipMemsetAsync(partial, 0, sizeof(double), stream);

    dim3 grid(IMG / BAND, 64);    // 32 bands x 64 images = 2048 blocks
    ssim_fused<<<grid, 256, 0, stream>>>(img1, img2, partial);
    ssim_finalize<<<1, 1, 0, stream>>>(partial, out);
}

// Round 8
// 227.804 us; speedup vs baseline: 1.6843x; 1.1800x over previous
//
#include <hip/hip_runtime.h>

// SSIM loss, fused single-pass — NO-LDS, NO-RING version.
// R7 post-mortem: even at launch_bounds(256,2) the allocator capped arch VGPRs
// at 128 and spilled the 80-float hrow ring to scratch (WRITE_SIZE 229 MB).
// Fix: delete the ring. Vertical running sums subtract a RECOMPUTED outgoing
// hrow (rows re-read 7 steps later are L1-resident: ~7 KB/wave working set).
// Recomputed H is bit-identical to the stored H, so numerics match R7.
// Live state: 10 running sums + 5 offsets + in-flight loads (~90 regs).
// No ring => no static-index full unroll needed => compact code, unroll 4.

constexpr int IMG = 512;
constexpr int BAND = 32;               // output rows per block
constexpr float C1 = 1.0e-4f;          // 0.01^2
constexpr float C2 = 9.0e-4f;          // 0.03^2
constexpr double INV_N = 1.0 / (64.0 * 512.0 * 512.0);

__global__ __launch_bounds__(256, 3)
void ssim_fused(const float* __restrict__ img1, const float* __restrict__ img2,
                double* __restrict__ partial) {
    __shared__ float wpart[4];

    const int tid = threadIdx.x;
    const int y0 = blockIdx.x * BAND;
    const size_t ib = (size_t)blockIdx.y * (IMG * IMG);
    const float* b1 = img1 + ib;
    const float* b2 = img2 + ib;

    // thread owns cols (2c, 2c+1); window union = floats [2c-4 .. 2c+5]
    const int xb = 2 * tid;
    const int xo0 = max(xb - 4, 0);          // clamped chunk offsets (stay in-row)
    const int xo1 = max(xb - 2, 0);
    const int xo2 = xb;
    const int xo3 = min(xb + 2, IMG - 2);
    const int xo4 = min(xb + 4, IMG - 2);
    const bool p0 = (xb - 4) >= 0;           // chunk-valid predicates
    const bool p1 = (xb - 2) >= 0;
    const bool p3 = (xb + 2) < IMG;
    const bool p4 = (xb + 4) < IMG;

    // vertical running 7-row sums, 5 quantities x 2 columns — the ONLY state
    float SA0 = 0, SA1 = 0, SB0 = 0, SB1 = 0, SAA0 = 0, SAA1 = 0,
          SBB0 = 0, SBB1 = 0, SAB0 = 0, SAB1 = 0;
    float acc = 0.f;

    // horizontal 7-tap sums of image row `row`, accumulated into S* with sign
    // sgn (+1 incoming, -1 outgoing). OOB rows contribute nothing (zero pad).
    auto hacc = [&](int row, float sgn) {
        if ((unsigned)row < (unsigned)IMG) {             // wave-uniform branch
            const float2 zz = make_float2(0.f, 0.f);
            const float* r1 = b1 + row * IMG;
            const float* r2 = b2 + row * IMG;
            float2 a0 = *(const float2*)(r1 + xo0);
            float2 a1 = *(const float2*)(r1 + xo1);
            float2 a2 = *(const float2*)(r1 + xo2);
            float2 a3 = *(const float2*)(r1 + xo3);
            float2 a4 = *(const float2*)(r1 + xo4);
            float2 c0 = *(const float2*)(r2 + xo0);
            float2 c1v = *(const float2*)(r2 + xo1);
            float2 c2v = *(const float2*)(r2 + xo2);
            float2 c3 = *(const float2*)(r2 + xo3);
            float2 c4 = *(const float2*)(r2 + xo4);
            a0 = p0 ? a0 : zz;  c0 = p0 ? c0 : zz;       // zero-pad x edges
            a1 = p1 ? a1 : zz;  c1v = p1 ? c1v : zz;
            a3 = p3 ? a3 : zz;  c3 = p3 ? c3 : zz;
            a4 = p4 ? a4 : zz;  c4 = p4 ? c4 : zz;

            float va1 = a0.y, va2 = a1.x, va3 = a1.y, va4 = a2.x,
                  va5 = a2.y, va6 = a3.x, va7 = a3.y, va8 = a4.x;
            float vb1 = c0.y, vb2 = c1v.x, vb3 = c1v.y, vb4 = c2v.x,
                  vb5 = c2v.y, vb6 = c3.x, vb7 = c3.y, vb8 = c4.x;

            float sA = ((va1 + va2) + (va3 + va4)) + ((va5 + va6) + va7);
            SA0 = fmaf(sgn, sA, SA0);
            SA1 = fmaf(sgn, (sA - va1) + va8, SA1);

            float sB = ((vb1 + vb2) + (vb3 + vb4)) + ((vb5 + vb6) + vb7);
            SB0 = fmaf(sgn, sB, SB0);
            SB1 = fmaf(sgn, (sB - vb1) + vb8, SB1);

            float q1 = va1 * va1;
            float sAA = fmaf(va7, va7, fmaf(va6, va6, fmaf(va5, va5,
                        fmaf(va4, va4, fmaf(va3, va3, fmaf(va2, va2, q1))))));
            SAA0 = fmaf(sgn, sAA, SAA0);
            SAA1 = fmaf(sgn, fmaf(va8, va8, sAA - q1), SAA1);

            float q2 = vb1 * vb1;
            float sBB = fmaf(vb7, vb7, fmaf(vb6, vb6, fmaf(vb5, vb5,
                        fmaf(vb4, vb4, fmaf(vb3, vb3, fmaf(vb2, vb2, q2))))));
            SBB0 = fmaf(sgn, sBB, SBB0);
            SBB1 = fmaf(sgn, fmaf(vb8, vb8, sBB - q2), SBB1);

            float q3 = va1 * vb1;
            float sAB = fmaf(va7, vb7, fmaf(va6, vb6, fmaf(va5, vb5,
                        fmaf(va4, vb4, fmaf(va3, vb3, fmaf(va2, vb2, q3))))));
            SAB0 = fmaf(sgn, sAB, SAB0);
            SAB1 = fmaf(sgn, fmaf(va8, vb8, sAB - q3), SAB1);
        }
    };

    // prime: window rows y0-3 .. y0+2
#pragma unroll
    for (int k = -3; k < 3; ++k) hacc(y0 + k, 1.f);

    // BAND output rows; moderate unroll — no ring, so no static-index need
#pragma unroll 4
    for (int t = 0; t < BAND; ++t) {
        hacc(y0 + t + 3, 1.f);    // incoming window row

        {   // SSIM, col 2c
            float m12 = SA0 * SB0, m11 = SA0 * SA0, m22 = SB0 * SB0;
            float num = fmaf(2.f, m12, C1) * fmaf(2.f, SAB0 - m12, C2);
            float den = (m11 + m22 + C1) * ((SAA0 - m11) + (SBB0 - m22) + C2);
            acc = fmaf(num, __builtin_amdgcn_rcpf(den), acc);
        }
        {   // SSIM, col 2c+1
            float m12 = SA1 * SB1, m11 = SA1 * SA1, m22 = SB1 * SB1;
            float num = fmaf(2.f, m12, C1) * fmaf(2.f, SAB1 - m12, C2);
            float den = (m11 + m22 + C1) * ((SAA1 - m11) + (SBB1 - m22) + C2);
            acc = fmaf(num, __builtin_amdgcn_rcpf(den), acc);
        }

        hacc(y0 + t - 3, -1.f);   // outgoing window row, recomputed (L1 hit)
    }

    // ---- reduce: wave shuffle -> LDS -> one double atomic per block ----
#pragma unroll
    for (int off = 32; off > 0; off >>= 1)
        acc += __shfl_xor(acc, off);
    if ((tid & 63) == 0) wpart[tid >> 6] = acc;
    __syncthreads();
    if (tid == 0)
        atomicAdd(partial, (double)((wpart[0] + wpart[1]) + (wpart[2] + wpart[3])));
}

__global__ void ssim_finalize(const double* __restrict__ partial,
                              float* __restrict__ out) {
    out[0] = (float)(1.0 - partial[0] * INV_N);
}

extern "C" void kernel_launch(void* const* d_in, const int* in_sizes, int n_in,
                              void* d_out, int out_size, void* d_ws, size_t ws_size,
                              hipStream_t stream) {
    const float* img1 = (const float*)d_in[0];
    const float* img2 = (const float*)d_in[1];
    float* out = (float*)d_out;
    double* partial = (double*)d_ws;

    hipMemsetAsync(partial, 0, sizeof(double), stream);

    dim3 grid(IMG / BAND, 64);    // 16 bands x 64 images = 1024 blocks
    ssim_fused<<<grid, 256, 0, stream>>>(img1, img2, partial);
    ssim_finalize<<<1, 1, 0, stream>>>(partial, out);
}